// Round 4
// baseline (862.110 us; speedup 1.0000x reference)
//
#include <hip/hip_runtime.h>

#define BLUR_H 256
#define BLUR_W 256
#define ROWS_PER_WAVE 64

// Horizontal 4-tap filter (coeffs 1,3,3,1 unscaled) on one row held as
// float4-per-lane across a 64-lane wave (64*4 = 256 = W).
// Padding: 2 zeros on the left, 1 zero on the right of the row.
__device__ inline float4 load_row_filtered(const float* __restrict__ xp,
                                           int ri, int col, int lane) {
    float4 v;
    if (ri >= 0 && ri < BLUR_H) {
        v = *reinterpret_cast<const float4*>(xp + (size_t)ri * BLUR_W + col);
    } else {
        v = make_float4(0.f, 0.f, 0.f, 0.f);
    }
    // Neighbors across lanes: prev lane's .z/.w, next lane's .x
    float pz = __shfl_up(v.z, 1);
    float pw = __shfl_up(v.w, 1);
    float n0 = __shfl_down(v.x, 1);
    if (lane == 0)  { pz = 0.f; pw = 0.f; }  // left zero-pad (2)
    if (lane == 63) { n0 = 0.f; }            // right zero-pad (1)

    float4 r;
    r.x = pz  + 3.f * pw  + 3.f * v.x + v.y;
    r.y = pw  + 3.f * v.x + 3.f * v.y + v.z;
    r.z = v.x + 3.f * v.y + 3.f * v.z + v.w;
    r.w = v.y + 3.f * v.z + 3.f * v.w + n0;
    return r;
}

__global__ __launch_bounds__(256) void Blur_86517821211771_kernel(
        const float* __restrict__ x, float* __restrict__ out, int nplanes) {
    const int tid  = threadIdx.x;
    const int wv   = tid >> 6;        // wave within block (0..3)
    const int lane = tid & 63;
    const int gw   = blockIdx.x * 4 + wv;      // global wave id
    const int plane   = gw >> 2;               // one 256x256 plane
    const int quarter = gw & 3;                // 64-row strip within plane
    if (plane >= nplanes) return;

    const float* xp = x   + (size_t)plane * (BLUR_H * BLUR_W);
    float*       op = out + (size_t)plane * (BLUR_H * BLUR_W);
    const int col = lane << 2;                 // 4 columns per lane
    const int r0  = quarter * ROWS_PER_WAVE;

    // Sliding 4-row window of horizontally filtered rows.
    // Output row i needs input rows i-2 .. i+1 (zero-padded outside [0,H)).
    float4 rm2 = load_row_filtered(xp, r0 - 2, col, lane);
    float4 rm1 = load_row_filtered(xp, r0 - 1, col, lane);
    float4 rc  = load_row_filtered(xp, r0,     col, lane);

    const float s = 1.f / 16.f;  // (1/4 horizontal) * (1/4 vertical)
    #pragma unroll 4
    for (int i = 0; i < ROWS_PER_WAVE; ++i) {
        float4 rp1 = load_row_filtered(xp, r0 + i + 1, col, lane);
        float4 o;
        o.x = (rm2.x + 3.f * rm1.x + 3.f * rc.x + rp1.x) * s;
        o.y = (rm2.y + 3.f * rm1.y + 3.f * rc.y + rp1.y) * s;
        o.z = (rm2.z + 3.f * rm1.z + 3.f * rc.z + rp1.z) * s;
        o.w = (rm2.w + 3.f * rm1.w + 3.f * rc.w + rp1.w) * s;
        *reinterpret_cast<float4*>(op + (size_t)(r0 + i) * BLUR_W + col) = o;
        rm2 = rm1; rm1 = rc; rc = rp1;
    }
}

extern "C" void kernel_launch(void* const* d_in, const int* in_sizes, int n_in,
                              void* d_out, int out_size, void* d_ws, size_t ws_size,
                              hipStream_t stream) {
    const float* x = (const float*)d_in[0];
    float* out = (float*)d_out;
    const int nplanes = in_sizes[0] / (BLUR_H * BLUR_W);   // B*C = 2048
    const int total_waves = nplanes * 4;                   // 4 row-strips per plane
    const int blocks = (total_waves + 3) / 4;              // 4 waves per block
    Blur_86517821211771_kernel<<<blocks, 256, 0, stream>>>(x, out, nplanes);
}